// Round 1
// baseline (1140.131 us; speedup 1.0000x reference)
//
#include <hip/hip_runtime.h>

#define B_    4
#define T_    256
#define U_    128
#define ENC_H 512
#define PRED_H 640
#define JH    640
#define V_    1025
#define VMAIN 1024

#define BM    64
#define KC    32
#define APITCH 40   // bf16 elems per LDS A row: 32 + 8 pad (80B, 2-way-free banking)
#define NKC   (JH / KC)   // 20

typedef float f32x4  __attribute__((ext_vector_type(4)));
typedef short bf16x8 __attribute__((ext_vector_type(8)));

__device__ __forceinline__ short bf16_rne(float x) {
    unsigned u = __float_as_uint(x);
    unsigned r = (u + 0x7fffu + ((u >> 16) & 1u)) >> 16;
    return (short)r;
}

// ---------------------------------------------------------------------------
// Small fp32 projection GEMM: Y[(b*M+m)][n] = sum_k X[b][k][m] * W[n][k] + bias[n]
// grid: (M/32, N/64, B), block 256. Tiles: 32m x 64n, KC=16.
// ---------------------------------------------------------------------------
__global__ __launch_bounds__(256) void proj_kernel(
    const float* __restrict__ X, const float* __restrict__ W,
    const float* __restrict__ bias, float* __restrict__ Y,
    int K, int M, int N)
{
    __shared__ float Xs[16][32];
    __shared__ float Ws[64][17];

    const int b  = blockIdx.z;
    const int m0 = blockIdx.x * 32;
    const int n0 = blockIdx.y * 64;
    const int tid = threadIdx.x;
    const int tx = tid & 15;   // n group (4 cols)
    const int ty = tid >> 4;   // m group (2 rows)

    const float* Xb = X + (size_t)b * K * M;

    float acc[2][4] = {{0.f,0.f,0.f,0.f},{0.f,0.f,0.f,0.f}};

    for (int k0 = 0; k0 < K; k0 += 16) {
        #pragma unroll
        for (int j = 0; j < 2; ++j) {
            int e = tid + j * 256;
            Xs[e >> 5][e & 31] = Xb[(size_t)(k0 + (e >> 5)) * M + m0 + (e & 31)];
        }
        #pragma unroll
        for (int j = 0; j < 4; ++j) {
            int e = tid + j * 256;
            Ws[e >> 4][e & 15] = W[(size_t)(n0 + (e >> 4)) * K + k0 + (e & 15)];
        }
        __syncthreads();
        #pragma unroll
        for (int k = 0; k < 16; ++k) {
            float a0 = Xs[k][ty * 2 + 0];
            float a1 = Xs[k][ty * 2 + 1];
            float b0 = Ws[tx * 4 + 0][k];
            float b1 = Ws[tx * 4 + 1][k];
            float b2 = Ws[tx * 4 + 2][k];
            float b3 = Ws[tx * 4 + 3][k];
            acc[0][0] += a0 * b0; acc[0][1] += a0 * b1;
            acc[0][2] += a0 * b2; acc[0][3] += a0 * b3;
            acc[1][0] += a1 * b0; acc[1][1] += a1 * b1;
            acc[1][2] += a1 * b2; acc[1][3] += a1 * b3;
        }
        __syncthreads();
    }

    #pragma unroll
    for (int i = 0; i < 2; ++i) {
        int m = m0 + ty * 2 + i;
        #pragma unroll
        for (int j = 0; j < 4; ++j) {
            int n = n0 + tx * 4 + j;
            Y[(size_t)(b * M + m) * N + n] = acc[i][j] + bias[n];
        }
    }
}

// ---------------------------------------------------------------------------
// fp32 -> bf16 convert (W_joint rows 0..1023)
// ---------------------------------------------------------------------------
__global__ __launch_bounds__(256) void cvt_kernel(
    const float* __restrict__ W, short* __restrict__ o, int n)
{
    int i = blockIdx.x * 256 + threadIdx.x;
    if (i < n) o[i] = bf16_rne(W[i]);
}

// ---------------------------------------------------------------------------
// Fused joint GEMM + log_softmax.
// grid.x = B*T*2 (each WG: one (b,t), 64 u-rows). block = 1024 (16 waves, 1x16).
// Each wave: 64 rows x 64 cols (4x4 tiles of 16x16x32 bf16 MFMA).
// A (hidden) staged in LDS dbuf; B (W_joint bf16) fragments direct from global/L2.
// Class 1024 computed fp32 in epilogue. Softmax fused via shuffles + LDS.
// ---------------------------------------------------------------------------
__global__ __launch_bounds__(1024) void joint_kernel(
    const float* __restrict__ f,       // [B*T][640]
    const float* __restrict__ g,       // [B*U][640]
    const short* __restrict__ wj,      // [1024][640] bf16
    const float* __restrict__ Wj32,    // [1025][640] fp32 (row 1024 used)
    const float* __restrict__ bj,      // [1025]
    float* __restrict__ out)           // [B*T*U][1025]
{
    __shared__ __align__(16) short As[2][BM * APITCH];  // 10.25 KB
    __shared__ float red[BM][16];                       // 4 KB
    __shared__ float zp[BM][16];                        // 4 KB
    __shared__ float rowmax_s[BM], lse_s[BM], z1024_s[BM];

    const int bt = blockIdx.x >> 1;
    const int uh = blockIdx.x & 1;
    const int b  = bt >> 8;             // T=256
    const int u0 = uh * BM;

    const float* frow = f + (size_t)bt * JH;
    const float* grow = g + (size_t)(b * U_ + u0) * JH;

    const int tid  = threadIdx.x;
    const int lane = tid & 63;
    const int wv   = tid >> 6;          // 0..15 col group
    const int q    = lane >> 4;         // quad
    const int l15  = lane & 15;

    // A-staging map: thread -> (u row, 2 consecutive k)
    const int su = tid >> 4;            // 0..63
    const int sk = (tid & 15) * 2;      // 0..30

    f32x4 acc[4][4];
    #pragma unroll
    for (int rt = 0; rt < 4; ++rt)
        #pragma unroll
        for (int ct = 0; ct < 4; ++ct)
            acc[rt][ct] = (f32x4){0.f, 0.f, 0.f, 0.f};

    // stage k-chunk 0
    {
        float f0 = frow[sk], f1 = frow[sk + 1];
        float g0 = grow[su * JH + sk], g1 = grow[su * JH + sk + 1];
        As[0][su * APITCH + sk]     = bf16_rne(fmaxf(f0 + g0, 0.f));
        As[0][su * APITCH + sk + 1] = bf16_rne(fmaxf(f1 + g1, 0.f));
    }
    __syncthreads();

    for (int kc = 0; kc < NKC; ++kc) {
        const int cur = kc & 1;
        const bool more = (kc + 1) < NKC;
        // prefetch next hidden chunk (global loads issue early)
        float h0 = 0.f, h1 = 0.f;
        if (more) {
            const int k0n = (kc + 1) * KC;
            float f0 = frow[k0n + sk], f1 = frow[k0n + sk + 1];
            float g0 = grow[su * JH + k0n + sk], g1 = grow[su * JH + k0n + sk + 1];
            h0 = fmaxf(f0 + g0, 0.f);
            h1 = fmaxf(f1 + g1, 0.f);
        }
        // B fragments direct from global (L2-resident W)
        const int k0 = kc * KC;
        bf16x8 bfr[4];
        #pragma unroll
        for (int ct = 0; ct < 4; ++ct) {
            const int col = (wv << 6) + (ct << 4) + l15;
            bfr[ct] = *(const bf16x8*)(wj + (size_t)col * JH + k0 + (q << 3));
        }
        // A fragments from LDS
        bf16x8 afr[4];
        #pragma unroll
        for (int rt = 0; rt < 4; ++rt)
            afr[rt] = *(const bf16x8*)(&As[cur][(rt * 16 + l15) * APITCH + (q << 3)]);
        #pragma unroll
        for (int rt = 0; rt < 4; ++rt)
            #pragma unroll
            for (int ct = 0; ct < 4; ++ct)
                acc[rt][ct] = __builtin_amdgcn_mfma_f32_16x16x32_bf16(
                    afr[rt], bfr[ct], acc[rt][ct], 0, 0, 0);
        // write next A buffer
        if (more) {
            const int ni = su * APITCH + sk;
            As[cur ^ 1][ni]     = bf16_rne(h0);
            As[cur ^ 1][ni + 1] = bf16_rne(h1);
        }
        __syncthreads();
    }

    // ---- epilogue: bias + fused log_softmax ----
    float mloc[4][4];
    #pragma unroll
    for (int rt = 0; rt < 4; ++rt)
        #pragma unroll
        for (int r = 0; r < 4; ++r) mloc[rt][r] = -3.0e38f;

    #pragma unroll
    for (int ct = 0; ct < 4; ++ct) {
        const float bb = bj[(wv << 6) + (ct << 4) + l15];
        #pragma unroll
        for (int rt = 0; rt < 4; ++rt)
            #pragma unroll
            for (int r = 0; r < 4; ++r) {
                acc[rt][ct][r] += bb;
                mloc[rt][r] = fmaxf(mloc[rt][r], acc[rt][ct][r]);
            }
    }
    // reduce max across the 16 lanes of each quad (they hold a row's 64 cols)
    #pragma unroll
    for (int off = 1; off < 16; off <<= 1)
        #pragma unroll
        for (int rt = 0; rt < 4; ++rt)
            #pragma unroll
            for (int r = 0; r < 4; ++r)
                mloc[rt][r] = fmaxf(mloc[rt][r], __shfl_xor(mloc[rt][r], off));
    if (l15 == 0) {
        #pragma unroll
        for (int rt = 0; rt < 4; ++rt)
            #pragma unroll
            for (int r = 0; r < 4; ++r)
                red[rt * 16 + (q << 2) + r][wv] = mloc[rt][r];
    }
    // class-1024 logit, fp32 (16 threads per row, 40 k each)
    {
        const int row  = tid >> 4;
        const int part = tid & 15;
        const float* w1024 = Wj32 + (size_t)VMAIN * JH;
        float s = 0.f;
        const int kb = part * 40;
        for (int kk = kb; kk < kb + 40; ++kk) {
            float h = fmaxf(frow[kk] + grow[row * JH + kk], 0.f);
            s += h * w1024[kk];
        }
        zp[row][part] = s;
    }
    __syncthreads();

    if (tid < BM) {
        float mx = red[tid][0];
        #pragma unroll
        for (int w = 1; w < 16; ++w) mx = fmaxf(mx, red[tid][w]);
        float z = bj[VMAIN];
        #pragma unroll
        for (int w = 0; w < 16; ++w) z += zp[tid][w];
        mx = fmaxf(mx, z);
        rowmax_s[tid] = mx;
        z1024_s[tid]  = z;
    }
    __syncthreads();

    float sloc[4][4];
    #pragma unroll
    for (int rt = 0; rt < 4; ++rt)
        #pragma unroll
        for (int r = 0; r < 4; ++r) {
            const float mx = rowmax_s[rt * 16 + (q << 2) + r];
            float s = 0.f;
            #pragma unroll
            for (int ct = 0; ct < 4; ++ct)
                s += __expf(acc[rt][ct][r] - mx);
            sloc[rt][r] = s;
        }
    #pragma unroll
    for (int off = 1; off < 16; off <<= 1)
        #pragma unroll
        for (int rt = 0; rt < 4; ++rt)
            #pragma unroll
            for (int r = 0; r < 4; ++r)
                sloc[rt][r] += __shfl_xor(sloc[rt][r], off);
    if (l15 == 0) {
        #pragma unroll
        for (int rt = 0; rt < 4; ++rt)
            #pragma unroll
            for (int r = 0; r < 4; ++r)
                red[rt * 16 + (q << 2) + r][wv] = sloc[rt][r];
    }
    __syncthreads();

    const size_t obase = (size_t)(bt * U_ + u0) * V_;
    if (tid < BM) {
        float tot = __expf(z1024_s[tid] - rowmax_s[tid]);
        #pragma unroll
        for (int w = 0; w < 16; ++w) tot += red[tid][w];
        float lse = rowmax_s[tid] + __logf(tot);
        lse_s[tid] = lse;
        out[obase + (size_t)tid * V_ + VMAIN] = z1024_s[tid] - lse;
    }
    __syncthreads();

    #pragma unroll
    for (int rt = 0; rt < 4; ++rt)
        #pragma unroll
        for (int r = 0; r < 4; ++r) {
            const int row = rt * 16 + (q << 2) + r;
            const float l = lse_s[row];
            #pragma unroll
            for (int ct = 0; ct < 4; ++ct) {
                const int col = (wv << 6) + (ct << 4) + l15;
                out[obase + (size_t)row * V_ + col] = acc[rt][ct][r] - l;
            }
        }
}

// ---------------------------------------------------------------------------
extern "C" void kernel_launch(void* const* d_in, const int* in_sizes, int n_in,
                              void* d_out, int out_size, void* d_ws, size_t ws_size,
                              hipStream_t stream) {
    const float* enc   = (const float*)d_in[0];
    const float* dec   = (const float*)d_in[1];
    const float* Wenc  = (const float*)d_in[2];
    const float* benc  = (const float*)d_in[3];
    const float* Wpred = (const float*)d_in[4];
    const float* bpred = (const float*)d_in[5];
    const float* Wj    = (const float*)d_in[6];
    const float* bjt   = (const float*)d_in[7];
    float* out = (float*)d_out;

    char* ws = (char*)d_ws;
    float* f_ws  = (float*)ws;                              // 1024*640 f32 = 2.62 MB
    float* g_ws  = (float*)(ws + 2621440);                  // 512*640 f32 = 1.31 MB
    short* wj_ws = (short*)(ws + 2621440 + 1310720);        // 1024*640 bf16 = 1.31 MB

    proj_kernel<<<dim3(8, 10, 4), 256, 0, stream>>>(enc, Wenc, benc, f_ws, ENC_H, T_, JH);
    proj_kernel<<<dim3(4, 10, 4), 256, 0, stream>>>(dec, Wpred, bpred, g_ws, PRED_H, U_, JH);
    cvt_kernel<<<dim3((VMAIN * JH + 255) / 256), 256, 0, stream>>>(Wj, wj_ws, VMAIN * JH);
    joint_kernel<<<dim3(B_ * T_ * 2), 1024, 0, stream>>>(f_ws, g_ws, wj_ws, Wj, bjt, out);
}